// Round 10
// baseline (299.763 us; speedup 1.0000x reference)
//
#include <hip/hip_runtime.h>

#define BB 128
#define NN 8192
#define SS 100
#define KK 512
#define SPLIT 50               // sample PAIRS per batch row (SPB=2)
#define NT 1024                // 16 waves
#define EPT 8                  // elements per thread per sample
#define CAND 512
#define NBIN 256

#define GIDX(e) (((e) >> 2) * 4096 + tid * 4 + ((e) & 3))

// LDS-only barrier: waits DS ops (lgkmcnt) but leaves global loads in
// flight (unlike __syncthreads, which drains vmcnt(0) too). All cross-wave
// communication here is via LDS. sched_barrier stops the compiler hoisting
// LDS reads above the wait (guide rule #18).
__device__ __forceinline__ void lds_barrier() {
    asm volatile("s_waitcnt lgkmcnt(0)" ::: "memory");
    __builtin_amdgcn_s_barrier();
    __builtin_amdgcn_sched_barrier(0);
}

// Hot map: [2,23] -> 1..255; p<2 -> 0 (implicit catch-all: skipped in the
// histogram, count recovered as K - sum(binned)). Threshold for K=512/8192
// sits at p~3.3 and count(p>=2)~1400 >> 512, so bin 0 is never selected on
// this data; exact level-2 refinement covers it anyway.
__device__ __forceinline__ int binHot(float p) {
    const float SC = 255.0f / 21.0f;
    const float OF = 1.0f - 2.0f * SC;
    int b = (int)fmaf(p, SC, OF);
    b = b < 0 ? 0 : b;
    return b > 255 ? 255 : b;
}
// Level-2 map: [-12,2] -> 0..255 (only used if catch-all selected).
__device__ __forceinline__ int binL2(float p) {
    const float SC = 256.0f / 14.0f;
    const float OF = 12.0f * SC;
    int b = (int)fmaf(p, SC, OF);
    b = b < 0 ? 0 : b;
    return b > 255 ? 255 : b;
}
__device__ __forceinline__ float fast_ln(float x) {
    return __builtin_amdgcn_logf(x) * 0.69314718056f;   // v_log_f32 * ln2
}
// Deterministic: bit-identical p everywhere it's computed.
__device__ __forceinline__ float p_of(float u, float lgv) {
    return lgv - fast_ln(-fast_ln(u + 1e-20f) + 1e-20f);
}

// One block = (b, pair of samples). 4 LDS-barriers per block; all global
// loads issued upfront and never drained by a barrier.
// MODE 0: write 2-bit-packed counts (u16/thread) to ws. MODE 1: atomicAdd out.
template <int MODE>
__global__ __launch_bounds__(NT, 8) void gumbel_topk_kernel(
    const float* __restrict__ logits,
    const float* __restrict__ uniform,
    unsigned short* __restrict__ ws,
    float* __restrict__ out) {

    __shared__ __align__(16) int histA[NBIN];
    __shared__ __align__(16) int histB[NBIN];
    __shared__ float ckA[CAND];
    __shared__ int   ciA[CAND];
    __shared__ float ckB[CAND];
    __shared__ int   ciB[CAND];
    __shared__ int bselA, bkkA, bselB, bkkB, cntA, cntB;

    const int tid  = threadIdx.x;
    const int lane = tid & 63;
    const int wv   = tid >> 6;
    const int b    = blockIdx.x / SPLIT;
    const int ch   = blockIdx.x % SPLIT;

    const float* lrow  = logits + (size_t)b * NN;
    const float* uArow = uniform + ((size_t)b * SS + ch * 2) * NN;
    const float* uBrow = uArow + NN;

    // ---- issue ALL global loads upfront; they stay in flight across s0
    float lg[EPT], pA[EPT], pB[EPT];
#pragma unroll
    for (int j = 0; j < 2; ++j) {
        *reinterpret_cast<float4*>(&pA[j * 4]) =
            *reinterpret_cast<const float4*>(&uArow[j * 4096 + tid * 4]);
        *reinterpret_cast<float4*>(&pB[j * 4]) =
            *reinterpret_cast<const float4*>(&uBrow[j * 4096 + tid * 4]);
        *reinterpret_cast<float4*>(&lg[j * 4]) =
            *reinterpret_cast<const float4*>(&lrow[j * 4096 + tid * 4]);
    }

    // ---- init LDS (256 ints per hist = 64 int4s)
    if (tid < 64)       *reinterpret_cast<int4*>(&histA[tid * 4])        = make_int4(0, 0, 0, 0);
    else if (tid < 128) *reinterpret_cast<int4*>(&histB[(tid - 64) * 4]) = make_int4(0, 0, 0, 0);
    else if (tid == 128) { cntA = 0; cntB = 0; }
    lds_barrier();                                        // s0

    // ---- transform + histogram (only p>=2 elements take an atomic)
#pragma unroll
    for (int e = 0; e < EPT; ++e) {
        pA[e] = p_of(pA[e], lg[e]);
        pB[e] = p_of(pB[e], lg[e]);
        const int bA = binHot(pA[e]);
        const int bBv = binHot(pB[e]);
        if (bA)  atomicAdd(&histA[bA], 1);
        if (bBv) atomicAdd(&histB[bBv], 1);
    }
    lds_barrier();                                        // s1

    // ---- single-wave scans: wave0 -> A, wave1 -> B (suffix, high->low).
    // Writes bsel=0,bkk=shortfall when total binned < target (cold case).
    auto scanWave = [&](const int* hist, int target, int* bsel, int* bkk) {
        const int4 h = *reinterpret_cast<const int4*>(&hist[lane * 4]);
        const int s4 = h.x + h.y + h.z + h.w;
        int suf = s4;
#pragma unroll
        for (int d = 1; d < 64; d <<= 1) {
            const int o = __shfl_down(suf, d);
            if (lane + d < 64) suf += o;
        }
        int cum = suf - s4;                  // strictly higher bins
        if (cum < target && cum + h.w >= target) { *bsel = lane * 4 + 3; *bkk = target - cum; }
        cum += h.w;
        if (cum < target && cum + h.z >= target) { *bsel = lane * 4 + 2; *bkk = target - cum; }
        cum += h.z;
        if (cum < target && cum + h.y >= target) { *bsel = lane * 4 + 1; *bkk = target - cum; }
        cum += h.y;
        if (cum < target && cum + h.x >= target) { *bsel = lane * 4 + 0; *bkk = target - cum; }
        cum += h.x;
        if (lane == 0 && cum < target) { *bsel = 0; *bkk = target - cum; }
    };
    if (wv == 0) scanWave(histA, KK, &bselA, &bkkA);
    if (wv == 1) scanWave(histB, KK, &bselB, &bkkB);
    lds_barrier();                                        // s2

    const int selA = bselA, kkA = bkkA;
    const int selB = bselB, kkB = bkkB;
    const bool coldA = (selA == 0), coldB = (selB == 0);
    int selA2 = 0, kkA2 = 0, selB2 = 0, kkB2 = 0;

    if (coldA || coldB) {
        // ---- exact level-2 refinement (block-uniform; never taken on this
        // data). All binned elements are members; take the kk shortfall from
        // below-floor elements via a second histogram over [-12,2].
        if (tid < 64)       *reinterpret_cast<int4*>(&histA[tid * 4])        = make_int4(0, 0, 0, 0);
        else if (tid < 128) *reinterpret_cast<int4*>(&histB[(tid - 64) * 4]) = make_int4(0, 0, 0, 0);
        lds_barrier();
#pragma unroll
        for (int e = 0; e < EPT; ++e) {
            if (coldA && binHot(pA[e]) == 0) atomicAdd(&histA[binL2(pA[e])], 1);
            if (coldB && binHot(pB[e]) == 0) atomicAdd(&histB[binL2(pB[e])], 1);
        }
        lds_barrier();
        if (wv == 0 && coldA) scanWave(histA, kkA, &bselA, &bkkA);
        if (wv == 1 && coldB) scanWave(histB, kkB, &bselB, &bkkB);
        lds_barrier();
        selA2 = bselA; kkA2 = bkkA;
        selB2 = bselB; kkB2 = bkkB;
    }

    // ---- collect threshold-bin candidates (~40/sample expected)
#pragma unroll
    for (int e = 0; e < EPT; ++e) {
        const int bA = binHot(pA[e]);
        const bool cA = coldA ? (bA == 0 && binL2(pA[e]) == selA2) : (bA == selA);
        if (cA) {
            const int pos = atomicAdd(&cntA, 1);
            if (pos < CAND) { ckA[pos] = pA[e]; ciA[pos] = GIDX(e); }
        }
        const int bBv = binHot(pB[e]);
        const bool cB = coldB ? (bBv == 0 && binL2(pB[e]) == selB2) : (bBv == selB);
        if (cB) {
            const int pos = atomicAdd(&cntB, 1);
            if (pos < CAND) { ckB[pos] = pB[e]; ciB[pos] = GIDX(e); }
        }
    }
    lds_barrier();                                        // s3

    // ---- membership: 2-bit count per element (A +1, B +1); in-bin elements
    // rank themselves against the candidate list (key desc, index asc).
    const int cA = cntA < CAND ? cntA : CAND;
    const int cB = cntB < CAND ? cntB : CAND;
    const int rkA = coldA ? kkA2 : kkA;
    const int rkB = coldB ? kkB2 : kkB;
    unsigned cnt8 = 0;
#pragma unroll
    for (int e = 0; e < EPT; ++e) {
        {
            const int b1 = binHot(pA[e]);
            int in = 0, tie = 0;
            if (coldA) {
                if (b1 > 0) in = 1;
                else { const int b2 = binL2(pA[e]); in = (b2 > selA2); tie = (b2 == selA2); }
            } else { in = (b1 > selA); tie = (b1 == selA); }
            if (tie) {
                const float kl = pA[e]; const int il = GIDX(e);
                int r = 0;
                for (int j = 0; j < cA; ++j)
                    r += (ckA[j] > kl || (ckA[j] == kl && ciA[j] < il)) ? 1 : 0;
                in = (r < rkA);
            }
            if (in) cnt8 += 1u << (2 * e);
        }
        {
            const int b1 = binHot(pB[e]);
            int in = 0, tie = 0;
            if (coldB) {
                if (b1 > 0) in = 1;
                else { const int b2 = binL2(pB[e]); in = (b2 > selB2); tie = (b2 == selB2); }
            } else { in = (b1 > selB); tie = (b1 == selB); }
            if (tie) {
                const float kl = pB[e]; const int il = GIDX(e);
                int r = 0;
                for (int j = 0; j < cB; ++j)
                    r += (ckB[j] > kl || (ckB[j] == kl && ciB[j] < il)) ? 1 : 0;
                in = (r < rkB);
            }
            if (in) cnt8 += 1u << (2 * e);
        }
    }

    if (MODE == 0) {
        ws[(size_t)blockIdx.x * NT + tid] = (unsigned short)cnt8;
    } else {
        float* orow = out + (size_t)b * NN;
#pragma unroll
        for (int e = 0; e < EPT; ++e) {
            const unsigned c = (cnt8 >> (2 * e)) & 3u;
            if (c) atomicAdd(orow + GIDX(e), (float)c * 0.01f);
        }
    }
}

// Sum 50 packed-2-bit partials per u16 position; each field <= 2, sum <= 100.
__global__ __launch_bounds__(256) void reduce_kernel(
    const unsigned short* __restrict__ ws, float* __restrict__ out) {
    const int g   = blockIdx.x * 256 + threadIdx.x;   // 0..131071
    const int b   = g >> 10;
    const int pos = g & 1023;
    int acc[8] = {0, 0, 0, 0, 0, 0, 0, 0};
    for (int ch = 0; ch < SPLIT; ++ch) {
        const unsigned w = ws[((size_t)(b * SPLIT + ch) << 10) + pos];
#pragma unroll
        for (int e = 0; e < 8; ++e) acc[e] += (w >> (2 * e)) & 3u;
    }
    float* ob = out + (size_t)b * NN;
    const float4 o0 = make_float4(acc[0] * 0.01f, acc[1] * 0.01f,
                                  acc[2] * 0.01f, acc[3] * 0.01f);
    const float4 o1 = make_float4(acc[4] * 0.01f, acc[5] * 0.01f,
                                  acc[6] * 0.01f, acc[7] * 0.01f);
    *reinterpret_cast<float4*>(&ob[pos * 4])        = o0;
    *reinterpret_cast<float4*>(&ob[4096 + pos * 4]) = o1;
}

extern "C" void kernel_launch(void* const* d_in, const int* in_sizes, int n_in,
                              void* d_out, int out_size, void* d_ws, size_t ws_size,
                              hipStream_t stream) {
    const float* logits  = (const float*)d_in[0];   // [128, 8192] f32
    const float* uniform = (const float*)d_in[1];   // [128, 100, 8192] f32
    float* out = (float*)d_out;                     // [128, 8192] f32

    const int grid = BB * SPLIT;                    // 6400 blocks
    const size_t need = (size_t)grid * NT * sizeof(unsigned short);  // 13.1 MB

    if (ws_size >= need) {
        gumbel_topk_kernel<0><<<grid, NT, 0, stream>>>(
            logits, uniform, (unsigned short*)d_ws, nullptr);
        reduce_kernel<<<(BB * NN / 8) / 256, 256, 0, stream>>>(
            (const unsigned short*)d_ws, out);
    } else {
        hipMemsetAsync(out, 0, (size_t)out_size * sizeof(float), stream);
        gumbel_topk_kernel<1><<<grid, NT, 0, stream>>>(
            logits, uniform, nullptr, out);
    }
}

// Round 11
// 187.802 us; speedup vs baseline: 1.5962x; 1.5962x over previous
//
#include <hip/hip_runtime.h>

#define BB 128
#define NN 8192
#define SS 100
#define KK 512
#define SPLIT 50               // sample PAIRS per batch row (SPB=2)
#define NT 1024                // 16 waves
#define EPT 8                  // elements per thread per sample
#define CAND 256
#define NBIN 2048

#define GIDX(e) (((e) >> 2) * 4096 + tid * 4 + ((e) & 3))
#define LN2 0.69314718056f

// LDS-only barrier: waits DS ops but leaves global loads in flight
// (__syncthreads drains vmcnt(0) too — guide §5). sched_barrier stops the
// compiler hoisting LDS reads above the wait (guide rule #18).
__device__ __forceinline__ void lds_barrier() {
    asm volatile("s_waitcnt lgkmcnt(0)" ::: "memory");
    __builtin_amdgcn_s_barrier();
    __builtin_amdgcn_sched_barrier(0);
}

// Deterministic fast p: log2-space inner, bit-identical at every callsite.
__device__ __forceinline__ float p_of(float u, float lgv) {
    const float g1 = __builtin_amdgcn_logf(u + 1e-20f);   // log2(u+eps)
    const float w  = fmaf(g1, -LN2, 1e-20f);              // -ln(u+eps)+eps
    const float g2 = __builtin_amdgcn_logf(w);            // log2(w)
    return fmaf(g2, -LN2, lgv);                           // lg - ln(w)
}

// Hot map: [2,23] -> 1..2047; p<2 -> 0 (implicit catch-all, skipped in the
// histogram; its count is recovered as the scan shortfall). K=512 threshold
// sits at p~3.3, count(p>=2)~1400 >> 512 -> bin 0 never selected on this
// data; exact level-2 refinement covers it anyway.
#define SCH (2046.0f / 21.0f)
#define OFH (1.0f - 2.0f * SCH)
__device__ __forceinline__ int binHot(float p) {
    int b = (int)fmaf(p, SCH, OFH);
    b = b < 0 ? 0 : b;
    return b > 2047 ? 2047 : b;
}
// Level-2 map: [-12,2] -> 0..2047 (only used if catch-all selected).
#define SC2 (2048.0f / 14.0f)
#define OF2 (12.0f * SC2)
__device__ __forceinline__ int binL2(float p) {
    int b = (int)fmaf(p, SC2, OF2);
    b = b < 0 ? 0 : b;
    return b > 2047 ? 2047 : b;
}

// One block = (b, pair of samples). 4 LDS barriers on the hot path; global
// loads are never drained by a barrier.
// MODE 0: write 2-bit-packed counts (u16/thread) to ws. MODE 1: atomicAdd out.
template <int MODE>
__global__ __launch_bounds__(NT, 8) void gumbel_topk_kernel(
    const float* __restrict__ logits,
    const float* __restrict__ uniform,
    unsigned short* __restrict__ ws,
    float* __restrict__ out) {

    __shared__ __align__(16) int histA[NBIN];
    __shared__ __align__(16) int histB[NBIN];
    __shared__ float ckA[CAND];
    __shared__ int   ciA[CAND];
    __shared__ float ckB[CAND];
    __shared__ int   ciB[CAND];
    __shared__ int bselA, bkkA, bselB, bkkB, cntA, cntB;

    const int tid  = threadIdx.x;
    const int lane = tid & 63;
    const int wv   = tid >> 6;
    const int b    = blockIdx.x / SPLIT;
    const int ch   = blockIdx.x % SPLIT;

    const float* lrow  = logits + (size_t)b * NN;
    const float* uArow = uniform + ((size_t)b * SS + ch * 2) * NN;
    const float* uBrow = uArow + NN;

    // ---- issue ALL global loads upfront; they stay in flight across s0
    float lg[EPT], pA[EPT], pB[EPT];
#pragma unroll
    for (int j = 0; j < 2; ++j) {
        *reinterpret_cast<float4*>(&pA[j * 4]) =
            *reinterpret_cast<const float4*>(&uArow[j * 4096 + tid * 4]);
        *reinterpret_cast<float4*>(&pB[j * 4]) =
            *reinterpret_cast<const float4*>(&uBrow[j * 4096 + tid * 4]);
        *reinterpret_cast<float4*>(&lg[j * 4]) =
            *reinterpret_cast<const float4*>(&lrow[j * 4096 + tid * 4]);
    }

    // ---- init LDS: 4096 ints over 1024 threads = one int4 each
    if (tid < 512) *reinterpret_cast<int4*>(&histA[tid * 4]) = make_int4(0, 0, 0, 0);
    else           *reinterpret_cast<int4*>(&histB[(tid - 512) * 4]) = make_int4(0, 0, 0, 0);
    if (tid == 0) { cntA = 0; cntB = 0; }
    lds_barrier();                                        // s0

    // ---- transform + histogram; keep only packed 16-bit bins (p regs die)
    unsigned bpA[EPT / 2], bpB[EPT / 2];
#pragma unroll
    for (int e = 0; e < EPT; ++e) {
        const float a  = p_of(pA[e], lg[e]);
        const float c  = p_of(pB[e], lg[e]);
        const int  bA  = binHot(a);
        const int  bBv = binHot(c);
        if (bA)  atomicAdd(&histA[bA], 1);
        if (bBv) atomicAdd(&histB[bBv], 1);
        if (e & 1) { bpA[e >> 1] |= (unsigned)bA << 16; bpB[e >> 1] |= (unsigned)bBv << 16; }
        else       { bpA[e >> 1]  = (unsigned)bA;       bpB[e >> 1]  = (unsigned)bBv; }
    }
    lds_barrier();                                        // s1

    // ---- single-wave scan (2048 bins, 8 chunk-sums/lane + 1 re-read).
    // Writes bsel=0,bkk=shortfall when total binned < target (cold case).
    auto scanWave = [&](const int* hist, int target, int* bsel, int* bkk) {
        int sq[8];
        int s = 0;
#pragma unroll
        for (int q = 0; q < 8; ++q) {
            const int4 h4 = *reinterpret_cast<const int4*>(&hist[lane * 32 + q * 4]);
            sq[q] = h4.x + h4.y + h4.z + h4.w;
            s += sq[q];
        }
        int suf = s;                         // inclusive suffix across lanes
#pragma unroll
        for (int d = 1; d < 64; d <<= 1) {
            const int o = __shfl_down(suf, d);
            if (lane + d < 64) suf += o;
        }
        int cum = suf - s;                   // strictly higher lanes' bins
        int fq = -1, fc = 0;
#pragma unroll
        for (int q = 7; q >= 0; --q) {
            if (cum < target && cum + sq[q] >= target) { fq = q; fc = cum; }
            cum += sq[q];
        }
        if (fq >= 0) {                        // crossing lane walks its chunk
            const int4 h4 = *reinterpret_cast<const int4*>(&hist[lane * 32 + fq * 4]);
            int c2 = fc;
            if (c2 < target && c2 + h4.w >= target) { *bsel = lane * 32 + fq * 4 + 3; *bkk = target - c2; }
            c2 += h4.w;
            if (c2 < target && c2 + h4.z >= target) { *bsel = lane * 32 + fq * 4 + 2; *bkk = target - c2; }
            c2 += h4.z;
            if (c2 < target && c2 + h4.y >= target) { *bsel = lane * 32 + fq * 4 + 1; *bkk = target - c2; }
            c2 += h4.y;
            if (c2 < target && c2 + h4.x >= target) { *bsel = lane * 32 + fq * 4 + 0; *bkk = target - c2; }
        }
        if (lane == 0 && cum < target) { *bsel = 0; *bkk = target - cum; }
    };
    if (wv == 0)      scanWave(histA, KK, &bselA, &bkkA);
    else if (wv == 1) scanWave(histB, KK, &bselB, &bkkB);
    lds_barrier();                                        // s2

    const int selA = bselA, kkA = bkkA;
    const int selB = bselB, kkB = bkkB;
    unsigned cnt8 = 0;

    if (selA > 0 && selB > 0) {
        // ================= HOT PATH =================
        // collect threshold-bin candidates (~5/sample); recompute keys from
        // L1/L2-hot scattered reloads (bit-identical p_of)
#pragma unroll
        for (int e = 0; e < EPT; ++e) {
            const int bA = (bpA[e >> 1] >> ((e & 1) * 16)) & 0xFFFF;
            if (bA == selA) {
                const int gi = GIDX(e);
                const float key = p_of(uArow[gi], lrow[gi]);
                const int pos = atomicAdd(&cntA, 1);
                if (pos < CAND) { ckA[pos] = key; ciA[pos] = gi; }
            }
            const int bBv = (bpB[e >> 1] >> ((e & 1) * 16)) & 0xFFFF;
            if (bBv == selB) {
                const int gi = GIDX(e);
                const float key = p_of(uBrow[gi], lrow[gi]);
                const int pos = atomicAdd(&cntB, 1);
                if (pos < CAND) { ckB[pos] = key; ciB[pos] = gi; }
            }
        }
        lds_barrier();                                    // s3

        const int cA = cntA < CAND ? cntA : CAND;
        const int cB = cntB < CAND ? cntB : CAND;
#pragma unroll
        for (int e = 0; e < EPT; ++e) {
            const int bA = (bpA[e >> 1] >> ((e & 1) * 16)) & 0xFFFF;
            if (bA > selA) {
                cnt8 += 1u << (2 * e);
            } else if (bA == selA) {
                const int gi = GIDX(e);
                const float kl = p_of(uArow[gi], lrow[gi]);
                int r = 0;
                for (int j = 0; j < cA; ++j)
                    r += (ckA[j] > kl || (ckA[j] == kl && ciA[j] < gi)) ? 1 : 0;
                if (r < kkA) cnt8 += 1u << (2 * e);
            }
            const int bBv = (bpB[e >> 1] >> ((e & 1) * 16)) & 0xFFFF;
            if (bBv > selB) {
                cnt8 += 1u << (2 * e);
            } else if (bBv == selB) {
                const int gi = GIDX(e);
                const float kl = p_of(uBrow[gi], lrow[gi]);
                int r = 0;
                for (int j = 0; j < cB; ++j)
                    r += (ckB[j] > kl || (ckB[j] == kl && ciB[j] < gi)) ? 1 : 0;
                if (r < kkB) cnt8 += 1u << (2 * e);
            }
        }
    } else {
        // ================= COLD PATH (exact; never taken on this data) ====
        const bool coldA = (selA == 0), coldB = (selB == 0);
        // re-materialize p for both samples (block-uniform branch)
#pragma unroll
        for (int j = 0; j < 2; ++j) {
            *reinterpret_cast<float4*>(&pA[j * 4]) =
                *reinterpret_cast<const float4*>(&uArow[j * 4096 + tid * 4]);
            *reinterpret_cast<float4*>(&pB[j * 4]) =
                *reinterpret_cast<const float4*>(&uBrow[j * 4096 + tid * 4]);
            *reinterpret_cast<float4*>(&lg[j * 4]) =
                *reinterpret_cast<const float4*>(&lrow[j * 4096 + tid * 4]);
        }
#pragma unroll
        for (int e = 0; e < EPT; ++e) { pA[e] = p_of(pA[e], lg[e]); pB[e] = p_of(pB[e], lg[e]); }
        if (tid < 512) *reinterpret_cast<int4*>(&histA[tid * 4]) = make_int4(0, 0, 0, 0);
        else           *reinterpret_cast<int4*>(&histB[(tid - 512) * 4]) = make_int4(0, 0, 0, 0);
        lds_barrier();
#pragma unroll
        for (int e = 0; e < EPT; ++e) {
            if (coldA && ((bpA[e >> 1] >> ((e & 1) * 16)) & 0xFFFF) == 0)
                atomicAdd(&histA[binL2(pA[e])], 1);
            if (coldB && ((bpB[e >> 1] >> ((e & 1) * 16)) & 0xFFFF) == 0)
                atomicAdd(&histB[binL2(pB[e])], 1);
        }
        lds_barrier();
        if (wv == 0 && coldA)      scanWave(histA, kkA, &bselA, &bkkA);
        else if (wv == 1 && coldB) scanWave(histB, kkB, &bselB, &bkkB);
        lds_barrier();
        const int selA2 = coldA ? bselA : 0, kkA2 = coldA ? bkkA : 0;
        const int selB2 = coldB ? bselB : 0, kkB2 = coldB ? bkkB : 0;

        // collect (cold: L2-bin ties among below-floor; hot sample: normal)
#pragma unroll
        for (int e = 0; e < EPT; ++e) {
            const int bA = (bpA[e >> 1] >> ((e & 1) * 16)) & 0xFFFF;
            const bool tA = coldA ? (bA == 0 && binL2(pA[e]) == selA2) : (bA == selA);
            if (tA) {
                const int pos = atomicAdd(&cntA, 1);
                if (pos < CAND) { ckA[pos] = pA[e]; ciA[pos] = GIDX(e); }
            }
            const int bBv = (bpB[e >> 1] >> ((e & 1) * 16)) & 0xFFFF;
            const bool tB = coldB ? (bBv == 0 && binL2(pB[e]) == selB2) : (bBv == selB);
            if (tB) {
                const int pos = atomicAdd(&cntB, 1);
                if (pos < CAND) { ckB[pos] = pB[e]; ciB[pos] = GIDX(e); }
            }
        }
        lds_barrier();

        const int cA = cntA < CAND ? cntA : CAND;
        const int cB = cntB < CAND ? cntB : CAND;
        const int rkA = coldA ? kkA2 : kkA;
        const int rkB = coldB ? kkB2 : kkB;
#pragma unroll
        for (int e = 0; e < EPT; ++e) {
            {
                const int b1 = (bpA[e >> 1] >> ((e & 1) * 16)) & 0xFFFF;
                int in = 0, tie = 0;
                if (coldA) {
                    if (b1 > 0) in = 1;
                    else { const int b2 = binL2(pA[e]); in = (b2 > selA2); tie = (b2 == selA2); }
                } else { in = (b1 > selA); tie = (b1 == selA); }
                if (tie) {
                    const float kl = pA[e]; const int il = GIDX(e);
                    int r = 0;
                    for (int j = 0; j < cA; ++j)
                        r += (ckA[j] > kl || (ckA[j] == kl && ciA[j] < il)) ? 1 : 0;
                    in = (r < rkA);
                }
                if (in) cnt8 += 1u << (2 * e);
            }
            {
                const int b1 = (bpB[e >> 1] >> ((e & 1) * 16)) & 0xFFFF;
                int in = 0, tie = 0;
                if (coldB) {
                    if (b1 > 0) in = 1;
                    else { const int b2 = binL2(pB[e]); in = (b2 > selB2); tie = (b2 == selB2); }
                } else { in = (b1 > selB); tie = (b1 == selB); }
                if (tie) {
                    const float kl = pB[e]; const int il = GIDX(e);
                    int r = 0;
                    for (int j = 0; j < cB; ++j)
                        r += (ckB[j] > kl || (ckB[j] == kl && ciB[j] < il)) ? 1 : 0;
                    in = (r < rkB);
                }
                if (in) cnt8 += 1u << (2 * e);
            }
        }
    }

    if (MODE == 0) {
        ws[(size_t)blockIdx.x * NT + tid] = (unsigned short)cnt8;
    } else {
        float* orow = out + (size_t)b * NN;
#pragma unroll
        for (int e = 0; e < EPT; ++e) {
            const unsigned c = (cnt8 >> (2 * e)) & 3u;
            if (c) atomicAdd(orow + GIDX(e), (float)c * 0.01f);
        }
    }
}

// Sum 50 packed-2-bit partials per u16 position; each field <= 2, sum <= 100.
__global__ __launch_bounds__(256) void reduce_kernel(
    const unsigned short* __restrict__ ws, float* __restrict__ out) {
    const int g   = blockIdx.x * 256 + threadIdx.x;   // 0..131071
    const int b   = g >> 10;
    const int pos = g & 1023;
    int acc[8] = {0, 0, 0, 0, 0, 0, 0, 0};
    for (int ch = 0; ch < SPLIT; ++ch) {
        const unsigned w = ws[((size_t)(b * SPLIT + ch) << 10) + pos];
#pragma unroll
        for (int e = 0; e < 8; ++e) acc[e] += (w >> (2 * e)) & 3u;
    }
    float* ob = out + (size_t)b * NN;
    const float4 o0 = make_float4(acc[0] * 0.01f, acc[1] * 0.01f,
                                  acc[2] * 0.01f, acc[3] * 0.01f);
    const float4 o1 = make_float4(acc[4] * 0.01f, acc[5] * 0.01f,
                                  acc[6] * 0.01f, acc[7] * 0.01f);
    *reinterpret_cast<float4*>(&ob[pos * 4])        = o0;
    *reinterpret_cast<float4*>(&ob[4096 + pos * 4]) = o1;
}

extern "C" void kernel_launch(void* const* d_in, const int* in_sizes, int n_in,
                              void* d_out, int out_size, void* d_ws, size_t ws_size,
                              hipStream_t stream) {
    const float* logits  = (const float*)d_in[0];   // [128, 8192] f32
    const float* uniform = (const float*)d_in[1];   // [128, 100, 8192] f32
    float* out = (float*)d_out;                     // [128, 8192] f32

    const int grid = BB * SPLIT;                    // 6400 blocks
    const size_t need = (size_t)grid * NT * sizeof(unsigned short);  // 13.1 MB

    if (ws_size >= need) {
        gumbel_topk_kernel<0><<<grid, NT, 0, stream>>>(
            logits, uniform, (unsigned short*)d_ws, nullptr);
        reduce_kernel<<<(BB * NN / 8) / 256, 256, 0, stream>>>(
            (const unsigned short*)d_ws, out);
    } else {
        hipMemsetAsync(out, 0, (size_t)out_size * sizeof(float), stream);
        gumbel_topk_kernel<1><<<grid, NT, 0, stream>>>(
            logits, uniform, nullptr, out);
    }
}

// Round 12
// 131.050 us; speedup vs baseline: 2.2874x; 1.4331x over previous
//
#include <hip/hip_runtime.h>

#define BB 128
#define NN 8192
#define SS 100
#define KK 512
#define SPLIT 50               // sample PAIRS per batch row (SPB=2)
#define NT 1024                // 16 waves
#define EPT 8                  // elements per thread per sample
#define CAND 256
#define NBIN 2048
#define NWAVE 16

#define GIDX(e) (((e) >> 2) * 4096 + tid * 4 + ((e) & 3))
#define LN2 0.69314718056f

// LDS-only barrier: waits DS ops but leaves global loads in flight
// (__syncthreads drains vmcnt(0) too — guide §5). sched_barrier stops the
// compiler hoisting LDS reads above the wait (guide rule #18).
__device__ __forceinline__ void lds_barrier() {
    asm volatile("s_waitcnt lgkmcnt(0)" ::: "memory");
    __builtin_amdgcn_s_barrier();
    __builtin_amdgcn_sched_barrier(0);
}

// Deterministic fast p: bit-identical at every callsite.
__device__ __forceinline__ float p_of(float u, float lgv) {
    const float g1 = __builtin_amdgcn_logf(u + 1e-20f);   // log2(u+eps)
    const float w  = fmaf(g1, -LN2, 1e-20f);              // -ln(u+eps)+eps
    const float g2 = __builtin_amdgcn_logf(w);            // log2(w)
    return fmaf(g2, -LN2, lgv);                           // lg - ln(w)
}

// Hot map: [2,23] -> 1..2047; p<2 -> 0 (skipped in the histogram; its count
// is recovered as the scan shortfall). K=512 threshold sits at p~3.3 and
// count(p>=2) ~ 1800 >> 512 (35 sigma), so bin 0 is never selected on this
// data; the exact level-2 refinement covers arbitrary inputs anyway.
#define SCH (2046.0f / 21.0f)
#define OFH (1.0f - 2.0f * SCH)
__device__ __forceinline__ int binHot(float p) {
    int b = (int)fmaf(p, SCH, OFH);
    b = b < 0 ? 0 : b;
    return b > 2047 ? 2047 : b;
}
// Level-2 map: [-12,2] -> 0..2047 (only used if catch-all selected).
#define SC2 (2048.0f / 14.0f)
#define OF2 (12.0f * SC2)
__device__ __forceinline__ int binL2(float p) {
    int b = (int)fmaf(p, SC2, OF2);
    b = b < 0 ? 0 : b;
    return b > 2047 ? 2047 : b;
}

// One block = (b, pair of samples). 5 LDS barriers on the hot path; global
// loads are never drained by a barrier. Structure = R9 + floor-skip.
// MODE 0: write 2-bit-packed counts (u16/thread) to ws. MODE 1: atomicAdd out.
template <int MODE>
__global__ __launch_bounds__(NT, 8) void gumbel_topk_kernel(
    const float* __restrict__ logits,
    const float* __restrict__ uniform,
    unsigned short* __restrict__ ws,
    float* __restrict__ out) {

    __shared__ __align__(16) int histA[NBIN];
    __shared__ __align__(16) int histB[NBIN];
    __shared__ float ckA[CAND];
    __shared__ int   ciA[CAND];
    __shared__ float ckB[CAND];
    __shared__ int   ciB[CAND];
    __shared__ int waveTotA[NWAVE], waveTotB[NWAVE];
    __shared__ int bselA, bkkA, bselB, bkkB, cntA, cntB;

    const int tid  = threadIdx.x;
    const int lane = tid & 63;
    const int wv   = tid >> 6;
    const int b    = blockIdx.x / SPLIT;
    const int ch   = blockIdx.x % SPLIT;

    const float* lrow  = logits + (size_t)b * NN;
    const float* uArow = uniform + ((size_t)b * SS + ch * 2) * NN;
    const float* uBrow = uArow + NN;

    // ---- issue ALL global loads upfront; they stay in flight across s0
    float lg[EPT], pA[EPT], pB[EPT];
#pragma unroll
    for (int j = 0; j < 2; ++j) {
        *reinterpret_cast<float4*>(&pA[j * 4]) =
            *reinterpret_cast<const float4*>(&uArow[j * 4096 + tid * 4]);
        *reinterpret_cast<float4*>(&pB[j * 4]) =
            *reinterpret_cast<const float4*>(&uBrow[j * 4096 + tid * 4]);
        *reinterpret_cast<float4*>(&lg[j * 4]) =
            *reinterpret_cast<const float4*>(&lrow[j * 4096 + tid * 4]);
    }

    // ---- init LDS: 4096 ints over 1024 threads = one int4 each
    if (tid < 512) *reinterpret_cast<int4*>(&histA[tid * 4]) = make_int4(0, 0, 0, 0);
    else           *reinterpret_cast<int4*>(&histB[(tid - 512) * 4]) = make_int4(0, 0, 0, 0);
    if (tid == 0) { cntA = 0; cntB = 0; }
    lds_barrier();                                        // s0

    // ---- transform + histogram; only p>=2 (~22%) takes an LDS atomic
#pragma unroll
    for (int e = 0; e < EPT; ++e) {
        pA[e] = p_of(pA[e], lg[e]);
        pB[e] = p_of(pB[e], lg[e]);
        const int bA  = binHot(pA[e]);
        const int bBv = binHot(pB[e]);
        if (bA)  atomicAdd(&histA[bA], 1);
        if (bBv) atomicAdd(&histB[bBv], 1);
    }
    lds_barrier();                                        // s1

    // ---- cross-wave scan of both hists (2 bins/thread), locate threshold
    // bins. Shortfall (total binned < target) selects bin 0 => cold path.
    // 2 barriers inside.
    auto scan2 = [&](int tA, int tB, bool doA, bool doB) {
        const int base = tid * 2;
        const int2 hA = *reinterpret_cast<const int2*>(&histA[base]);
        const int2 hB = *reinterpret_cast<const int2*>(&histB[base]);
        const int sumA = hA.x + hA.y, sumB = hB.x + hB.y;
        int sufA = sumA, sufB = sumB;
#pragma unroll
        for (int d = 1; d < 64; d <<= 1) {
            const int oA = __shfl_down(sufA, d);
            const int oB = __shfl_down(sufB, d);
            if (lane + d < 64) { sufA += oA; sufB += oB; }
        }
        if (lane == 0) { waveTotA[wv] = sufA; waveTotB[wv] = sufB; }
        lds_barrier();                                    // sX
        int cumA = sufA - sumA, cumB = sufB - sumB;
        for (int w2 = wv + 1; w2 < NWAVE; ++w2) { cumA += waveTotA[w2]; cumB += waveTotB[w2]; }
        if (doA) {
            if (cumA < tA && cumA + hA.y >= tA) { bselA = base + 1; bkkA = tA - cumA; }
            const int c2 = cumA + hA.y;
            if (c2 < tA && c2 + hA.x >= tA)     { bselA = base;     bkkA = tA - c2; }
            if (tid == 0 && c2 + hA.x < tA)     { bselA = 0;        bkkA = tA - (c2 + hA.x); }
        }
        if (doB) {
            if (cumB < tB && cumB + hB.y >= tB) { bselB = base + 1; bkkB = tB - cumB; }
            const int c2 = cumB + hB.y;
            if (c2 < tB && c2 + hB.x >= tB)     { bselB = base;     bkkB = tB - c2; }
            if (tid == 0 && c2 + hB.x < tB)     { bselB = 0;        bkkB = tB - (c2 + hB.x); }
        }
        lds_barrier();                                    // sY
    };
    scan2(KK, KK, true, true);                            // s2, s3

    const int selA = bselA, kkA = bkkA;
    const int selB = bselB, kkB = bkkB;
    const bool coldA = (selA == 0), coldB = (selB == 0);
    int selA2 = 0, kkA2 = 0, selB2 = 0, kkB2 = 0;

    if (coldA || coldB) {
        // ---- exact level-2 refinement (block-uniform; never taken on this
        // data). All hot-binned elements are members; take the shortfall
        // from below-floor elements via a second histogram over [-12,2].
        if (tid < 512) *reinterpret_cast<int4*>(&histA[tid * 4]) = make_int4(0, 0, 0, 0);
        else           *reinterpret_cast<int4*>(&histB[(tid - 512) * 4]) = make_int4(0, 0, 0, 0);
        lds_barrier();
#pragma unroll
        for (int e = 0; e < EPT; ++e) {
            if (coldA && binHot(pA[e]) == 0) atomicAdd(&histA[binL2(pA[e])], 1);
            if (coldB && binHot(pB[e]) == 0) atomicAdd(&histB[binL2(pB[e])], 1);
        }
        lds_barrier();
        scan2(kkA, kkB, coldA, coldB);
        selA2 = bselA; kkA2 = bkkA;
        selB2 = bselB; kkB2 = bkkB;
    }

    // ---- collect threshold-bin candidates (~5/sample; keys from live p)
#pragma unroll
    for (int e = 0; e < EPT; ++e) {
        const int bA = binHot(pA[e]);
        const bool tA = coldA ? (bA == 0 && binL2(pA[e]) == selA2) : (bA == selA);
        if (tA) {
            const int pos = atomicAdd(&cntA, 1);
            if (pos < CAND) { ckA[pos] = pA[e]; ciA[pos] = GIDX(e); }
        }
        const int bBv = binHot(pB[e]);
        const bool tB = coldB ? (bBv == 0 && binL2(pB[e]) == selB2) : (bBv == selB);
        if (tB) {
            const int pos = atomicAdd(&cntB, 1);
            if (pos < CAND) { ckB[pos] = pB[e]; ciB[pos] = GIDX(e); }
        }
    }
    lds_barrier();                                        // s4

    // ---- membership: 2-bit count per element (A +1, B +1); in-bin elements
    // rank themselves against the candidate list (key desc, index asc).
    const int cA = cntA < CAND ? cntA : CAND;
    const int cB = cntB < CAND ? cntB : CAND;
    const int rkA = coldA ? kkA2 : kkA;
    const int rkB = coldB ? kkB2 : kkB;
    unsigned cnt8 = 0;
#pragma unroll
    for (int e = 0; e < EPT; ++e) {
        {
            const int b1 = binHot(pA[e]);
            int in = 0, tie = 0;
            if (coldA) {
                if (b1 > 0) in = 1;
                else { const int b2 = binL2(pA[e]); in = (b2 > selA2); tie = (b2 == selA2); }
            } else { in = (b1 > selA); tie = (b1 == selA); }
            if (tie) {
                const float kl = pA[e]; const int il = GIDX(e);
                int r = 0;
                for (int j = 0; j < cA; ++j)
                    r += (ckA[j] > kl || (ckA[j] == kl && ciA[j] < il)) ? 1 : 0;
                in = (r < rkA);
            }
            if (in) cnt8 += 1u << (2 * e);
        }
        {
            const int b1 = binHot(pB[e]);
            int in = 0, tie = 0;
            if (coldB) {
                if (b1 > 0) in = 1;
                else { const int b2 = binL2(pB[e]); in = (b2 > selB2); tie = (b2 == selB2); }
            } else { in = (b1 > selB); tie = (b1 == selB); }
            if (tie) {
                const float kl = pB[e]; const int il = GIDX(e);
                int r = 0;
                for (int j = 0; j < cB; ++j)
                    r += (ckB[j] > kl || (ckB[j] == kl && ciB[j] < il)) ? 1 : 0;
                in = (r < rkB);
            }
            if (in) cnt8 += 1u << (2 * e);
        }
    }

    if (MODE == 0) {
        ws[(size_t)blockIdx.x * NT + tid] = (unsigned short)cnt8;
    } else {
        float* orow = out + (size_t)b * NN;
#pragma unroll
        for (int e = 0; e < EPT; ++e) {
            const unsigned c = (cnt8 >> (2 * e)) & 3u;
            if (c) atomicAdd(orow + GIDX(e), (float)c * 0.01f);
        }
    }
}

// Sum 50 packed-2-bit partials per u16 position; each field <= 2, sum <= 100.
__global__ __launch_bounds__(256) void reduce_kernel(
    const unsigned short* __restrict__ ws, float* __restrict__ out) {
    const int g   = blockIdx.x * 256 + threadIdx.x;   // 0..131071
    const int b   = g >> 10;
    const int pos = g & 1023;
    int acc[8] = {0, 0, 0, 0, 0, 0, 0, 0};
    for (int ch = 0; ch < SPLIT; ++ch) {
        const unsigned w = ws[((size_t)(b * SPLIT + ch) << 10) + pos];
#pragma unroll
        for (int e = 0; e < 8; ++e) acc[e] += (w >> (2 * e)) & 3u;
    }
    float* ob = out + (size_t)b * NN;
    const float4 o0 = make_float4(acc[0] * 0.01f, acc[1] * 0.01f,
                                  acc[2] * 0.01f, acc[3] * 0.01f);
    const float4 o1 = make_float4(acc[4] * 0.01f, acc[5] * 0.01f,
                                  acc[6] * 0.01f, acc[7] * 0.01f);
    *reinterpret_cast<float4*>(&ob[pos * 4])        = o0;
    *reinterpret_cast<float4*>(&ob[4096 + pos * 4]) = o1;
}

extern "C" void kernel_launch(void* const* d_in, const int* in_sizes, int n_in,
                              void* d_out, int out_size, void* d_ws, size_t ws_size,
                              hipStream_t stream) {
    const float* logits  = (const float*)d_in[0];   // [128, 8192] f32
    const float* uniform = (const float*)d_in[1];   // [128, 100, 8192] f32
    float* out = (float*)d_out;                     // [128, 8192] f32

    const int grid = BB * SPLIT;                    // 6400 blocks
    const size_t need = (size_t)grid * NT * sizeof(unsigned short);  // 13.1 MB

    if (ws_size >= need) {
        gumbel_topk_kernel<0><<<grid, NT, 0, stream>>>(
            logits, uniform, (unsigned short*)d_ws, nullptr);
        reduce_kernel<<<(BB * NN / 8) / 256, 256, 0, stream>>>(
            (const unsigned short*)d_ws, out);
    } else {
        hipMemsetAsync(out, 0, (size_t)out_size * sizeof(float), stream);
        gumbel_topk_kernel<1><<<grid, NT, 0, stream>>>(
            logits, uniform, nullptr, out);
    }
}